// Round 1
// baseline (466.045 us; speedup 1.0000x reference)
//
#include <hip/hip_runtime.h>
#include <hip/hip_bf16.h>
#include <math.h>

// ---------------------------------------------------------------------------
// ThreeHeadedDecoder: batch-1 LSTM decoder step, all matvecs (HBM-bound).
// V=50257, E=512, H=1024, C=1024, L=1024, S=2048, NL=2
//
// ws layout (floats):
//   [0,1024)      h_0
//   [1024,2048)   h_1            (also concat_in[0:1024])
//   [2048,5120)   ctx_out[3][1024] = lctx,rctx,lemma (concat_in[1024:4096])
//   [5120,8192)   v[3][1024]
//   [8192,14336)  e[3][2048]
//   [20480,21504) concat_out[1024]
// ---------------------------------------------------------------------------

#define WS_H0        0
#define WS_CONCAT_IN 1024          // h_1 lives here
#define WS_CTXOUT    2048
#define WS_V         5120
#define WS_E         8192
#define WS_COUT      20480
#define OUT_V        50257

__device__ __forceinline__ float wave_sum(float v) {
#pragma unroll
    for (int o = 32; o > 0; o >>= 1) v += __shfl_down(v, o, 64);
    return v;
}

__device__ __forceinline__ float dot4(float4 a, float4 b) {
    return a.x * b.x + a.y * b.y + a.z * b.z + a.w * b.w;
}

__device__ __forceinline__ float sigmoidf_(float x) {
    return 1.0f / (1.0f + expf(-x));
}

// One block per LSTM unit k (1024 blocks). Wave w computes gate row w*1024+k.
__global__ __launch_bounds__(256) void lstm_kernel(
    const float* __restrict__ x_base, const int* __restrict__ ids, int E_in,
    const float* __restrict__ W_ih, const float* __restrict__ W_hh,
    const float* __restrict__ b_ih, const float* __restrict__ b_hh,
    const float* __restrict__ hprev, const float* __restrict__ cprev,
    float* __restrict__ h_ws, float* __restrict__ h_out, float* __restrict__ c_out,
    float* __restrict__ zero_base, int zero_count)
{
    // fused zero-init of ws accumulation regions (for later atomicAdd phases)
    if (zero_base != nullptr) {
        int idx = blockIdx.x * 256 + threadIdx.x;
        if (idx < zero_count) zero_base[idx] = 0.0f;
    }

    const float* x = (ids != nullptr) ? (x_base + (size_t)512 * (size_t)ids[0]) : x_base;

    const int k = blockIdx.x;          // unit [0,1024)
    const int w = threadIdx.x >> 6;    // wave 0..3 -> gate i,f,g,o
    const int lane = threadIdx.x & 63;
    const int row = w * 1024 + k;

    float acc = 0.0f;
    {
        const float4* r4 = (const float4*)(W_ih + (size_t)row * E_in);
        const float4* x4 = (const float4*)x;
        const int n4 = E_in >> 2;
        for (int i = lane; i < n4; i += 64) acc += dot4(r4[i], x4[i]);
    }
    {
        const float4* r4 = (const float4*)(W_hh + (size_t)row * 1024);
        const float4* h4 = (const float4*)hprev;
        for (int i = lane; i < 256; i += 64) acc += dot4(r4[i], h4[i]);
    }
    acc = wave_sum(acc);

    __shared__ float g[4];
    if (lane == 0) g[w] = acc + b_ih[row] + b_hh[row];
    __syncthreads();
    if (threadIdx.x == 0) {
        float i_ = sigmoidf_(g[0]);
        float f_ = sigmoidf_(g[1]);
        float g_ = tanhf(g[2]);
        float o_ = sigmoidf_(g[3]);
        float c_new = f_ * cprev[k] + i_ * g_;
        float h_new = o_ * tanhf(c_new);
        h_ws[k] = h_new;
        h_out[k] = h_new;
        c_out[k] = c_new;
    }
}

// v[a][c] = sum_h W_a[h][c] * q[h].  Grid: 3*64 blocks; block = (a, 16-row chunk).
// Thread t owns columns 4t..4t+3; atomicAdd partials into v (zeroed by lstm_kernel).
__global__ __launch_bounds__(256) void attn_v_kernel(
    const float* __restrict__ W0, const float* __restrict__ W1,
    const float* __restrict__ W2, const float* __restrict__ q,
    float* __restrict__ v)
{
    const int a = blockIdx.x >> 6;
    const int chunk = blockIdx.x & 63;
    const float* W = (a == 0) ? W0 : (a == 1) ? W1 : W2;
    const int c = threadIdx.x * 4;
    float4 acc = make_float4(0.f, 0.f, 0.f, 0.f);
    const int h0 = chunk * 16;
#pragma unroll 4
    for (int h = h0; h < h0 + 16; ++h) {
        float qh = q[h];
        float4 wv = *(const float4*)(W + (size_t)h * 1024 + c);
        acc.x += wv.x * qh; acc.y += wv.y * qh;
        acc.z += wv.z * qh; acc.w += wv.w * qh;
    }
    float* vd = v + a * 1024 + c;
    atomicAdd(vd + 0, acc.x); atomicAdd(vd + 1, acc.y);
    atomicAdd(vd + 2, acc.z); atomicAdd(vd + 3, acc.w);
}

// e[a][s] = ctx_a[s][:] . v[a][:]   (6144 wave-dots; grid 1536 x 256)
__global__ __launch_bounds__(256) void attn_e_kernel(
    const float* __restrict__ C0, const float* __restrict__ C1,
    const float* __restrict__ C2, const float* __restrict__ v,
    float* __restrict__ e)
{
    const int wid = (blockIdx.x * 256 + threadIdx.x) >> 6;
    const int lane = threadIdx.x & 63;
    if (wid >= 3 * 2048) return;
    const int a = wid >> 11;
    const int s = wid & 2047;
    const float* ctx = (a == 0) ? C0 : (a == 1) ? C1 : C2;
    const float4* r4 = (const float4*)(ctx + (size_t)s * 1024);
    const float4* v4 = (const float4*)(v + a * 1024);
    float acc = 0.0f;
    for (int i = lane; i < 256; i += 64) acc += dot4(r4[i], v4[i]);
    acc = wave_sum(acc);
    if (lane == 0) e[a * 2048 + s] = acc;
}

// softmax over e[a][:] (recomputed per block, cheap/L2-hot) then
// ctx_out[a][c] += sum_s p[s]*ctx[s][c] over this block's 32-row chunk.
__global__ __launch_bounds__(256) void attn_ctx_kernel(
    const float* __restrict__ C0, const float* __restrict__ C1,
    const float* __restrict__ C2, const float* __restrict__ e,
    float* __restrict__ ctx_out)
{
    const int a = blockIdx.x >> 6;
    const int chunk = blockIdx.x & 63;
    const float* ctx = (a == 0) ? C0 : (a == 1) ? C1 : C2;
    const float* ea = e + a * 2048;

    __shared__ float red[256];
    const int t = threadIdx.x;
    float m = -1e30f;
    for (int i = t; i < 2048; i += 256) m = fmaxf(m, ea[i]);
    red[t] = m; __syncthreads();
    for (int o = 128; o > 0; o >>= 1) {
        if (t < o) red[t] = fmaxf(red[t], red[t + o]);
        __syncthreads();
    }
    m = red[0]; __syncthreads();

    float ssum = 0.0f;
    for (int i = t; i < 2048; i += 256) ssum += expf(ea[i] - m);
    red[t] = ssum; __syncthreads();
    for (int o = 128; o > 0; o >>= 1) {
        if (t < o) red[t] += red[t + o];
        __syncthreads();
    }
    const float inv = 1.0f / red[0];

    const int c = t * 4;
    float4 acc = make_float4(0.f, 0.f, 0.f, 0.f);
    const int s0 = chunk * 32;
    for (int s = s0; s < s0 + 32; ++s) {
        float wgt = expf(ea[s] - m) * inv;
        float4 cv = *(const float4*)(ctx + (size_t)s * 1024 + c);
        acc.x += wgt * cv.x; acc.y += wgt * cv.y;
        acc.z += wgt * cv.z; acc.w += wgt * cv.w;
    }
    float* od = ctx_out + a * 1024 + c;
    atomicAdd(od + 0, acc.x); atomicAdd(od + 1, acc.y);
    atomicAdd(od + 2, acc.z); atomicAdd(od + 3, acc.w);
}

// concat_out[j] = tanh(W_concat[j][:] . concat_in + b[j])  (1024 wave-dots of 4096)
__global__ __launch_bounds__(256) void concat_kernel(
    const float* __restrict__ W, const float* __restrict__ b,
    const float* __restrict__ cin, float* __restrict__ cout)
{
    const int w = threadIdx.x >> 6;
    const int lane = threadIdx.x & 63;
    const int j = blockIdx.x * 4 + w;
    const float4* r4 = (const float4*)(W + (size_t)j * 4096);
    const float4* x4 = (const float4*)cin;
    float acc = 0.0f;
    for (int i = lane; i < 1024; i += 64) acc += dot4(r4[i], x4[i]);
    acc = wave_sum(acc);
    if (lane == 0) cout[j] = tanhf(acc + b[j]);
}

// logits[vrow] = W_out[vrow][:] . concat_out + b_out[vrow]  (50257 wave-dots)
__global__ __launch_bounds__(256) void out_kernel(
    const float* __restrict__ W, const float* __restrict__ b,
    const float* __restrict__ x, float* __restrict__ out)
{
    const int wid = (blockIdx.x * 256 + threadIdx.x) >> 6;
    const int lane = threadIdx.x & 63;
    const int nwaves = gridDim.x * 4;
    const float4* x4 = (const float4*)x;
    for (int vrow = wid; vrow < OUT_V; vrow += nwaves) {
        const float4* r4 = (const float4*)(W + (size_t)vrow * 1024);
        float acc = 0.0f;
        for (int i = lane; i < 256; i += 64) acc += dot4(r4[i], x4[i]);
        acc = wave_sum(acc);
        if (lane == 0) out[vrow] = acc + b[vrow];
    }
}

extern "C" void kernel_launch(void* const* d_in, const int* in_sizes, int n_in,
                              void* d_out, int out_size, void* d_ws, size_t ws_size,
                              hipStream_t stream) {
    const int*   input_ids = (const int*)  d_in[0];
    const float* h0        = (const float*)d_in[1];   // [2,1,1024]
    const float* c0        = (const float*)d_in[2];
    const float* lctx      = (const float*)d_in[3];   // [2048,1024]
    const float* rctx      = (const float*)d_in[4];
    const float* lemma     = (const float*)d_in[5];
    const float* emb       = (const float*)d_in[6];   // [50257,512]
    const float* W_ih0     = (const float*)d_in[7];
    const float* W_hh0     = (const float*)d_in[8];
    const float* b_ih0     = (const float*)d_in[9];
    const float* b_hh0     = (const float*)d_in[10];
    const float* W_ih1     = (const float*)d_in[11];
    const float* W_hh1     = (const float*)d_in[12];
    const float* b_ih1     = (const float*)d_in[13];
    const float* b_hh1     = (const float*)d_in[14];
    const float* W_left    = (const float*)d_in[15];
    const float* b_left    = (const float*)d_in[16];  // dropped: softmax-invariant
    const float* W_right   = (const float*)d_in[17];
    const float* W_lemma   = (const float*)d_in[19];
    const float* W_concat  = (const float*)d_in[21];
    const float* b_concat  = (const float*)d_in[22];
    const float* W_out     = (const float*)d_in[23];
    const float* b_out     = (const float*)d_in[24];
    (void)b_left; (void)in_sizes; (void)n_in; (void)out_size; (void)ws_size;

    float* out = (float*)d_out;
    float* ws  = (float*)d_ws;

    // d_out layout: logits[50257], h_new[2][1024], c_new[2][1024]
    float* h0_out = out + OUT_V;
    float* h1_out = out + OUT_V + 1024;
    float* c0_out = out + OUT_V + 2048;
    float* c1_out = out + OUT_V + 3072;

    // K1: LSTM layer 0 (+ zero the atomic accumulation regions [2048,8192))
    lstm_kernel<<<1024, 256, 0, stream>>>(
        emb, input_ids, 512, W_ih0, W_hh0, b_ih0, b_hh0,
        h0, c0, ws + WS_H0, h0_out, c0_out,
        ws + WS_CTXOUT, 6144 /* ctx_out(3k) + v(3k) */);

    // K2: LSTM layer 1
    lstm_kernel<<<1024, 256, 0, stream>>>(
        ws + WS_H0, nullptr, 1024, W_ih1, W_hh1, b_ih1, b_hh1,
        h0 + 1024, c0 + 1024, ws + WS_CONCAT_IN, h1_out, c1_out,
        nullptr, 0);

    // K3: v_a = q @ W_a  (b·q term dropped — constant under softmax)
    attn_v_kernel<<<192, 256, 0, stream>>>(
        W_left, W_right, W_lemma, ws + WS_CONCAT_IN, ws + WS_V);

    // K4: e[a][s] = ctx_a[s] . v_a
    attn_e_kernel<<<1536, 256, 0, stream>>>(
        lctx, rctx, lemma, ws + WS_V, ws + WS_E);

    // K5: softmax + weighted context sum
    attn_ctx_kernel<<<192, 256, 0, stream>>>(
        lctx, rctx, lemma, ws + WS_E, ws + WS_CTXOUT);

    // K6: concat projection + tanh
    concat_kernel<<<256, 256, 0, stream>>>(
        W_concat, b_concat, ws + WS_CONCAT_IN, ws + WS_COUT);

    // K7: vocab projection (206 MB — the roofline term)
    out_kernel<<<2048, 256, 0, stream>>>(
        W_out, b_out, ws + WS_COUT, out);
}